// Round 10
// baseline (276.712 us; speedup 1.0000x reference)
//
#include <hip/hip_runtime.h>

#define NI 2048
#define NB 64
#define NC 32
#define DC 16
#define DI 8

static constexpr float SQ_EPS = 1e-7f;

// SSA vector type: first-class LLVM vector -> never an alloca, never scratch.
typedef float f8 __attribute__((ext_vector_type(8)));

// Routing pass v11 — BARRIER-FREE: W streamed per-wave from global.
// Session facts (v1-v10): occupancy pinned ~2 waves/EU for all non-spill
// configs; hand pipelines inside barriers spill (v9); v1's 8 barrier-
// drained staging phases serialize the pipes (pipe-sum ~35 us vs 51
// measured). Exit: the W-LDS staging exists only to share W across the
// block's 4 waves — but lane (c,dg)'s fragment is 256 B CONTIGUOUS in
// global W (W[c][i][dg*8..+7][:]). So each wave loads its own W directly:
// 16 dwordx4/lane/i, full line utilization, from L2/L3 (W = 32 MB,
// L3-resident; 4x wave redundancy = 512 MB/pass ~ 15 us at L2-class BW).
// Zero barriers in the loop -> one straight-line 16-i sweep the compiler
// can schedule/hoist freely (the only pipelining this toolchain does
// well). x stays in LDS (v6 lesson), staged once, ONE barrier total.
// waves_per_eu(1,2): min=1 -> 256-reg codegen budget (law: 256/min);
// max=2 = the residency we observe anyway.
// Grid (128 i-blocks, 4 b-quarters) x 256 threads (4 waves).
// Wave w owns b-quad by*16 + w*4 + {0..3}; sweeps i0..i0+15.
// Lane = (c = lane&31, dg = lane>>5); u[dd] = output dim d = dg*8+dd.
// MODE 0: uniform coupling 1/32. MODE 1: logits = dot(u, veff),
// veff transposed [b][dg][c][8].
template <int MODE>
__global__
__attribute__((amdgpu_flat_work_group_size(256, 256), amdgpu_waves_per_eu(1, 2)))
void route_pass(
    const float* __restrict__ x, const float* __restrict__ W,
    const float* __restrict__ veff, float* __restrict__ partial)
{
    __shared__ f8 xbuf[256];        // [brel 16][iloc 16] = 8 KB, staged once

    const int tid   = threadIdx.x;
    const int wave  = tid >> 6;
    const int lane  = tid & 63;
    const int c     = lane & 31;
    const int dg    = lane >> 5;
    const int brel0 = wave * 4;
    const int b0    = blockIdx.y * 16 + brel0;    // wave's b-quad base
    const int i0    = blockIdx.x * 16;

    f8 s0 = {}, s1 = {}, s2 = {}, s3 = {};

    // veff fragments for the 4 b's (MODE 1), transposed [b][dg][c][8]
    f8 va = {}, vb = {}, vc = {}, vd = {};
    if (MODE == 1) {
        va = *reinterpret_cast<const f8*>(veff + (((size_t)(b0+0)*2 + dg)*32 + c)*8);
        vb = *reinterpret_cast<const f8*>(veff + (((size_t)(b0+1)*2 + dg)*32 + c)*8);
        vc = *reinterpret_cast<const f8*>(veff + (((size_t)(b0+2)*2 + dg)*32 + c)*8);
        vd = *reinterpret_cast<const f8*>(veff + (((size_t)(b0+3)*2 + dg)*32 + c)*8);
    }

    // ---- stage x once: 512 float4 over 256 threads (coalesced 512 B/b-row)
    {
        float4* xb4 = reinterpret_cast<float4*>(xbuf);
        const float4* xg = reinterpret_cast<const float4*>(x);
        const int t0 = tid, t1 = tid + 256;
        // f4 idx = brel*32 + r  <->  global (b*NI + i0)*2 + r,  r = t&31
        xb4[t0] = xg[((size_t)(blockIdx.y*16 + (t0>>5)) * NI + i0)*2 + (t0&31)];
        xb4[t1] = xg[((size_t)(blockIdx.y*16 + (t1>>5)) * NI + i0)*2 + (t1&31)];
    }
    __syncthreads();                 // the ONLY barrier

    // lane's W stream: 64 consecutive floats per i at wbase + ii*128
    const float* wbase = W + ((size_t)c * NI + i0) * 128 + dg * 64;

#pragma unroll 2
    for (int ii = 0; ii < 16; ++ii) {
        const float* wp = wbase + (size_t)ii * 128;
        // x broadcast reads (wave-uniform LDS addresses)
        const f8 xa = xbuf[(brel0+0)*16 + ii];
        const f8 xb = xbuf[(brel0+1)*16 + ii];
        const f8 xc = xbuf[(brel0+2)*16 + ii];
        const f8 xd = xbuf[(brel0+3)*16 + ii];

        f8 u0 = {}, u1 = {}, u2 = {}, u3 = {};
#pragma unroll
        for (int dd = 0; dd < 8; ++dd) {
            const f8 wv = *reinterpret_cast<const f8*>(wp + dd * 8);
            float a0 = 0.f, a1 = 0.f, a2 = 0.f, a3 = 0.f;
#pragma unroll
            for (int j = 0; j < 8; ++j) {
                a0 += wv[j] * xa[j];
                a1 += wv[j] * xb[j];
                a2 += wv[j] * xc[j];
                a3 += wv[j] * xd[j];
            }
            u0[dd] = a0; u1[dd] = a1; u2[dd] = a2; u3[dd] = a3;
        }

        if (MODE == 0) {
            const float cu = 1.0f / 32.0f;
            s0 += u0 * cu; s1 += u1 * cu; s2 += u2 * cu; s3 += u3 * cu;
        } else {
            // Pair-softmax: lower 32-half reduces the even b, upper the
            // odd b, concurrently; one xor-32 merge in, one xor-32
            // coef-swap out. 12 shuffles + 1 exp per pair.
#pragma unroll
            for (int pr = 0; pr < 2; ++pr) {
                const f8& ue = pr ? u2 : u0;
                const f8& uo = pr ? u3 : u1;
                const f8& ve = pr ? vc : va;
                const f8& vo = pr ? vd : vb;
                float pe = 0.0f, po = 0.0f;
#pragma unroll
                for (int k = 0; k < 8; ++k) {
                    pe += ue[k] * ve[k];
                    po += uo[k] * vo[k];
                }
                // route partial of the OTHER half's b across, keep mine
                const float send = (dg == 0) ? po : pe;
                const float recv = __shfl_xor(send, 32);
                float a = ((dg == 0) ? pe : po) + recv;  // full logit
                float m = a;
#pragma unroll
                for (int off = 16; off >= 1; off >>= 1)
                    m = fmaxf(m, __shfl_xor(m, off));
                const float e = __expf(a - m);
                float t = e;
#pragma unroll
                for (int off = 16; off >= 1; off >>= 1)
                    t += __shfl_xor(t, off);
                const float mine  = e / t;
                const float other = __shfl_xor(mine, 32);
                const float ce = (dg == 0) ? mine : other;
                const float co = (dg == 0) ? other : mine;
                if (pr == 0) { s0 += u0 * ce; s1 += u1 * co; }
                else         { s2 += u2 * ce; s3 += u3 * co; }
            }
        }
    }

    // ---- flush the wave's four s-partials (plain coalesced 32 B stores)
    // partial floats: [pblk 512][brel 16][dg 2][c 32][8]
    {
        const int pblk = blockIdx.y * gridDim.x + blockIdx.x;   // 0..511
        float* gp = partial +
            (((size_t)pblk * 16 + brel0) * 128 + dg * 64 + c * 2) * 4;
        *reinterpret_cast<f8*>(gp)        = s0;
        *reinterpret_cast<f8*>(gp +  512) = s1;
        *reinterpret_cast<f8*>(gp + 1024) = s2;
        *reinterpret_cast<f8*>(gp + 1536) = s3;
    }
}

// Fused 128-way partial reduction + squash, float4-vectorized.
// 64 blocks x 512 threads (proven ~6 us): tid -> (ibq = tid>>7 sums 32 of
// the 128 i-block slabs; sub = tid&127 -> (c, dq)). 4-way LDS tree then
// squash on tid<128.
// phase 1: veff  = NI * squash(s)   (transposed layout [b][dg][c][8])
// phase 2: veff += NI * squash(s)
// phase 3: out   = squash(s)        (canonical [b][c][d])
__global__ __launch_bounds__(512) void reduce_squash(
    const float* __restrict__ partial, float* __restrict__ veff,
    float* __restrict__ out, int phase)
{
    __shared__ float4 red[512];
    const int b   = blockIdx.x;
    const int sub = threadIdx.x & 127;
    const int ibq = threadIdx.x >> 7;        // i-block quarter
    const int c   = (sub >> 2) & 31;
    const int dq  = sub & 3;                 // d-quad: d = dq*4 + j

    // slab layout: [by*128 + ib][brel 16][dg 2][c 32][8]
    const float* base = partial
        + ((size_t)(b >> 4) * 2048 + (b & 15)) * 512
        + (dq >> 1) * 256 + c * 8 + (dq & 1) * 4
        + (size_t)ibq * 32 * 8192;
    float4 acc = make_float4(0.f, 0.f, 0.f, 0.f);
#pragma unroll 8
    for (int ib = 0; ib < 32; ++ib) {
        const float4 p = *reinterpret_cast<const float4*>(base + (size_t)ib * 8192);
        acc.x += p.x; acc.y += p.y; acc.z += p.z; acc.w += p.w;
    }
    red[threadIdx.x] = acc;
    __syncthreads();
    if (threadIdx.x < 128) {
        const float4 a1 = red[sub + 128];
        const float4 a2 = red[sub + 256];
        const float4 a3 = red[sub + 384];
        acc.x += a1.x + a2.x + a3.x;
        acc.y += a1.y + a2.y + a3.y;
        acc.z += a1.z + a2.z + a3.z;
        acc.w += a1.w + a2.w + a3.w;

        // |s|^2 across the 4 d-quads (dq = low 2 bits of lane id)
        float sq = acc.x*acc.x + acc.y*acc.y + acc.z*acc.z + acc.w*acc.w;
        sq += __shfl_xor(sq, 1);
        sq += __shfl_xor(sq, 2);
        const float scale = sq / ((1.0f + sq) * sqrtf(sq + SQ_EPS));

        if (phase == 3) {
            float4* op = reinterpret_cast<float4*>(out + ((size_t)b * NC + c) * DC + dq * 4);
            *op = make_float4(scale*acc.x, scale*acc.y, scale*acc.z, scale*acc.w);
        } else {
            const float ns = scale * (float)NI;
            float4* vp = reinterpret_cast<float4*>(
                veff + (((size_t)b * 2 + (dq >> 1)) * 32 + c) * 8 + (dq & 1) * 4);
            if (phase == 1) {
                *vp = make_float4(ns*acc.x, ns*acc.y, ns*acc.z, ns*acc.w);
            } else {
                float4 old = *vp;
                *vp = make_float4(old.x + ns*acc.x, old.y + ns*acc.y,
                                  old.z + ns*acc.z, old.w + ns*acc.w);
            }
        }
    }
}

extern "C" void kernel_launch(void* const* d_in, const int* in_sizes, int n_in,
                              void* d_out, int out_size, void* d_ws, size_t ws_size,
                              hipStream_t stream) {
    (void)in_sizes; (void)n_in; (void)out_size; (void)ws_size;
    const float* x = (const float*)d_in[0];
    const float* W = (const float*)d_in[1];

    float* partial = (float*)d_ws;      // 512 slabs x 32 KB = 16 MiB
    float* veff    = (float*)d_out;     // scratch; phase-3 squash overwrites

    const dim3 grid(128, 4);

    // ---- iteration 1: uniform coupling
    route_pass<0><<<grid, 256, 0, stream>>>(x, W, nullptr, partial);
    reduce_squash<<<64, 512, 0, stream>>>(partial, veff, nullptr, 1);

    // ---- iteration 2: logits = NI * <u, v1>
    route_pass<1><<<grid, 256, 0, stream>>>(x, W, veff, partial);
    reduce_squash<<<64, 512, 0, stream>>>(partial, veff, nullptr, 2);

    // ---- iteration 3: logits = NI * (<u, v1> + <u, v2>)
    route_pass<1><<<grid, 256, 0, stream>>>(x, W, veff, partial);
    reduce_squash<<<64, 512, 0, stream>>>(partial, nullptr, (float*)d_out, 3);
}

// Round 11
// 195.515 us; speedup vs baseline: 1.4153x; 1.4153x over previous
//
#include <hip/hip_runtime.h>

#define NI 2048
#define NB 64
#define NC 32
#define DC 16
#define DI 8

static constexpr float SQ_EPS = 1e-7f;

// SSA vector type: first-class LLVM vector -> never an alloca, never scratch.
typedef float f8 __attribute__((ext_vector_type(8)));

// Routing pass v12 — async W staging via global_load_lds, double-buffered.
// Ledger (v1-v11): occupancy pinned ~2 waves/EU (all hint/shape variants);
// reg-staged pipelines spill (v9); global-W per-lane streaming is wave-
// uncoalesced (v11, 70 us). Remaining gap vs pipe-sum (~12 us/pass) =
// staging latency exposed at barriers. Fix with the one proven mechanism
// not yet tried: global_load_lds (DMA global->LDS, no VGPRs -> spill-
// impossible, no ds_write instrs). Issue round r+1's tile BEFORE computing
// round r; the barrier's implicit vmcnt(0) is then nearly free (m97).
// DMA dest is wave-uniform base + lane*16 (linear) -> pad-33 layout
// replaced by ROTATION layout: f4 slot(q,cc) = q*32 + ((cc+q)&31),
// q = (il*16+k10)*2+kdg. Linear in 64-slot chunks (DMA-ok); the rotation
// staggers the 4-dword bank window by 4 per q = same conflict profile as
// the pad (4-way max, measured negligible). Source per lane = inverse map
// (global side of global_load_lds is per-lane arbitrary).
// Structure: v5's 8 rounds x 2-i tiles, dbuf wbuf[2][2048]f4 (2x32 KB) +
// x staged once (8 KB) = 72 KB -> 2 blocks/CU; ONE barrier/round (v5: 2).
// Attrs: proven (2,2) -> 128-reg budget, ~100-reg live set, no spill.
// Grid (128 i-blocks, 4 b-quarters) x 256 threads (4 waves).
// Wave w owns b-quad by*16 + w*4 + {0..3}; sweeps i0..i0+15.
// Lane = (c = lane&31, dg = lane>>5).
// MODE 0: uniform coupling 1/32. MODE 1: logits = dot(u, veff),
// veff transposed [b][dg][c][8].
template <int MODE>
__global__
__attribute__((amdgpu_flat_work_group_size(256, 256), amdgpu_waves_per_eu(2, 2)))
void route_pass(
    const float* __restrict__ x, const float* __restrict__ W,
    const float* __restrict__ veff, float* __restrict__ partial)
{
    __shared__ float4 wbuf[2][2048];   // rotation layout, 2 x 32 KB
    __shared__ float4 xbuf[512];       // [brel 16][iloc 16][2] = 8 KB, once

    const int tid   = threadIdx.x;
    const int wave  = tid >> 6;
    const int lane  = tid & 63;
    const int c     = lane & 31;
    const int dg    = lane >> 5;
    const int brel0 = wave * 4;
    const int b0    = blockIdx.y * 16 + brel0;    // wave's b-quad base
    const int i0    = blockIdx.x * 16;

    const float4* Wf4 = reinterpret_cast<const float4*>(W);

    f8 s0 = {}, s1 = {}, s2 = {}, s3 = {};

    // veff fragments for the 4 b's (MODE 1), transposed [b][dg][c][8]
    f8 va = {}, vb = {}, vc = {}, vd = {};
    if (MODE == 1) {
        va = *reinterpret_cast<const f8*>(veff + (((size_t)(b0+0)*2 + dg)*32 + c)*8);
        vb = *reinterpret_cast<const f8*>(veff + (((size_t)(b0+1)*2 + dg)*32 + c)*8);
        vc = *reinterpret_cast<const f8*>(veff + (((size_t)(b0+2)*2 + dg)*32 + c)*8);
        vd = *reinterpret_cast<const f8*>(veff + (((size_t)(b0+3)*2 + dg)*32 + c)*8);
    }

    // ---- async stage of one 2-i W tile into wbuf[buf] via global_load_lds.
    // slot s (f4): q = s>>5 (0..63), cpos = s&31, cc = (cpos-q)&31,
    // il = q>>5, k10 = (q>>1)&15, kdg = q&1, k = k10 + 16*kdg;
    // global f4 = (cc*NI + itile + il)*32 + k.
    // Per wave-op: 64 lanes x 16B -> 1 KB linear at slot base o*256+wave*64.
#define STAGE_ASYNC(buf, itile)                                              \
    {                                                                        \
        _Pragma("unroll")                                                    \
        for (int o = 0; o < 8; ++o) {                                        \
            const int s  = o * 256 + wave * 64 + lane;                       \
            const int q  = s >> 5;                                           \
            const int cc = ((s & 31) - q) & 31;                              \
            const int il = q >> 5;                                           \
            const int k  = ((q >> 1) & 15) + ((q & 1) << 4);                 \
            const float4* srcp = Wf4 + ((size_t)cc * NI + (itile) + il) * 32 + k; \
            __builtin_amdgcn_global_load_lds(                                \
                (const __attribute__((address_space(1))) void*)srcp,         \
                (__attribute__((address_space(3))) void*)&wbuf[buf][o * 256 + wave * 64], \
                16, 0, 0);                                                   \
        }                                                                    \
    }

    // ---- prologue: issue tile 0; stage x once (coalesced 512 B per b-row)
    STAGE_ASYNC(0, i0);
    {
        const float4* xg = reinterpret_cast<const float4*>(x);
        const int t0 = tid, t1 = tid + 256;
        // slot = brel*32 + iloc*2 + half  <->  ((by*16+brel)*NI+i0+iloc)*2+half
        xbuf[t0] = xg[((size_t)(blockIdx.y*16 + (t0>>5)) * NI + i0 + ((t0&31)>>1))*2 + (t0&1)];
        xbuf[t1] = xg[((size_t)(blockIdx.y*16 + (t1>>5)) * NI + i0 + ((t1&31)>>1))*2 + (t1&1)];
    }
    __syncthreads();      // drains DMA (tile 0 ready) + xbuf visible

    int cur = 0;
    for (int rnd = 0; rnd < 8; ++rnd) {
        // issue next tile first: latency hides under this round's compute
        if (rnd < 7) STAGE_ASYNC(cur ^ 1, i0 + (rnd + 1) * 2);

        const float4* wb = wbuf[cur];

#pragma unroll
        for (int il = 0; il < 2; ++il) {
            const int iloc = rnd * 2 + il;
            // x broadcast reads (wave-uniform LDS addresses)
            const float4 xa0 = xbuf[(brel0+0)*32 + iloc*2], xa1 = xbuf[(brel0+0)*32 + iloc*2+1];
            const float4 xb0 = xbuf[(brel0+1)*32 + iloc*2], xb1 = xbuf[(brel0+1)*32 + iloc*2+1];
            const float4 xc0 = xbuf[(brel0+2)*32 + iloc*2], xc1 = xbuf[(brel0+2)*32 + iloc*2+1];
            const float4 xd0 = xbuf[(brel0+3)*32 + iloc*2], xd1 = xbuf[(brel0+3)*32 + iloc*2+1];

            f8 u0 = {}, u1 = {}, u2 = {}, u3 = {};
#pragma unroll
            for (int dd = 0; dd < 8; ++dd) {
                const int ql = (il * 16 + dd * 2) * 2 + dg;
                const int qh = ql + 2;
                const float4 wl = wb[ql * 32 + ((c + ql) & 31)];
                const float4 wh = wb[qh * 32 + ((c + qh) & 31)];
                u0[dd] = wl.x*xa0.x + wl.y*xa0.y + wl.z*xa0.z + wl.w*xa0.w
                       + wh.x*xa1.x + wh.y*xa1.y + wh.z*xa1.z + wh.w*xa1.w;
                u1[dd] = wl.x*xb0.x + wl.y*xb0.y + wl.z*xb0.z + wl.w*xb0.w
                       + wh.x*xb1.x + wh.y*xb1.y + wh.z*xb1.z + wh.w*xb1.w;
                u2[dd] = wl.x*xc0.x + wl.y*xc0.y + wl.z*xc0.z + wl.w*xc0.w
                       + wh.x*xc1.x + wh.y*xc1.y + wh.z*xc1.z + wh.w*xc1.w;
                u3[dd] = wl.x*xd0.x + wl.y*xd0.y + wl.z*xd0.z + wl.w*xd0.w
                       + wh.x*xd1.x + wh.y*xd1.y + wh.z*xd1.z + wh.w*xd1.w;
            }

            if (MODE == 0) {
                const float cu = 1.0f / 32.0f;
                s0 += u0 * cu; s1 += u1 * cu; s2 += u2 * cu; s3 += u3 * cu;
            } else {
                // Pair-softmax: lower 32-half reduces the even b, upper the
                // odd b, concurrently; one xor-32 merge in, one xor-32
                // coef-swap out. 12 shuffles + 1 exp per pair.
#pragma unroll
                for (int pr = 0; pr < 2; ++pr) {
                    const f8& ue = pr ? u2 : u0;
                    const f8& uo = pr ? u3 : u1;
                    const f8& ve = pr ? vc : va;
                    const f8& vo = pr ? vd : vb;
                    float pe = 0.0f, po = 0.0f;
#pragma unroll
                    for (int kk = 0; kk < 8; ++kk) {
                        pe += ue[kk] * ve[kk];
                        po += uo[kk] * vo[kk];
                    }
                    // route partial of the OTHER half's b across, keep mine
                    const float send = (dg == 0) ? po : pe;
                    const float recv = __shfl_xor(send, 32);
                    float a = ((dg == 0) ? pe : po) + recv;  // full logit
                    float m = a;
#pragma unroll
                    for (int off = 16; off >= 1; off >>= 1)
                        m = fmaxf(m, __shfl_xor(m, off));
                    const float e = __expf(a - m);
                    float t = e;
#pragma unroll
                    for (int off = 16; off >= 1; off >>= 1)
                        t += __shfl_xor(t, off);
                    const float mine  = e / t;
                    const float other = __shfl_xor(mine, 32);
                    const float ce = (dg == 0) ? mine : other;
                    const float co = (dg == 0) ? other : mine;
                    if (pr == 0) { s0 += u0 * ce; s1 += u1 * co; }
                    else         { s2 += u2 * ce; s3 += u3 * co; }
                }
            }
        }

        __syncthreads();   // drains vmcnt (next tile landed under compute)
        cur ^= 1;          // + all readers of wbuf[cur] done
    }
#undef STAGE_ASYNC

    // ---- flush the wave's four s-partials (plain coalesced 32 B stores)
    // partial floats: [pblk 512][brel 16][dg 2][c 32][8]
    {
        const int pblk = blockIdx.y * gridDim.x + blockIdx.x;   // 0..511
        float* gp = partial +
            (((size_t)pblk * 16 + brel0) * 128 + dg * 64 + c * 2) * 4;
        *reinterpret_cast<f8*>(gp)        = s0;
        *reinterpret_cast<f8*>(gp +  512) = s1;
        *reinterpret_cast<f8*>(gp + 1024) = s2;
        *reinterpret_cast<f8*>(gp + 1536) = s3;
    }
}

// Fused 128-way partial reduction + squash, float4-vectorized.
// 64 blocks x 512 threads (proven ~6 us): tid -> (ibq = tid>>7 sums 32 of
// the 128 i-block slabs; sub = tid&127 -> (c, dq)). 4-way LDS tree then
// squash on tid<128.
// phase 1: veff  = NI * squash(s)   (transposed layout [b][dg][c][8])
// phase 2: veff += NI * squash(s)
// phase 3: out   = squash(s)        (canonical [b][c][d])
__global__ __launch_bounds__(512) void reduce_squash(
    const float* __restrict__ partial, float* __restrict__ veff,
    float* __restrict__ out, int phase)
{
    __shared__ float4 red[512];
    const int b   = blockIdx.x;
    const int sub = threadIdx.x & 127;
    const int ibq = threadIdx.x >> 7;        // i-block quarter
    const int c   = (sub >> 2) & 31;
    const int dq  = sub & 3;                 // d-quad: d = dq*4 + j

    // slab layout: [by*128 + ib][brel 16][dg 2][c 32][8]
    const float* base = partial
        + ((size_t)(b >> 4) * 2048 + (b & 15)) * 512
        + (dq >> 1) * 256 + c * 8 + (dq & 1) * 4
        + (size_t)ibq * 32 * 8192;
    float4 acc = make_float4(0.f, 0.f, 0.f, 0.f);
#pragma unroll 8
    for (int ib = 0; ib < 32; ++ib) {
        const float4 p = *reinterpret_cast<const float4*>(base + (size_t)ib * 8192);
        acc.x += p.x; acc.y += p.y; acc.z += p.z; acc.w += p.w;
    }
    red[threadIdx.x] = acc;
    __syncthreads();
    if (threadIdx.x < 128) {
        const float4 a1 = red[sub + 128];
        const float4 a2 = red[sub + 256];
        const float4 a3 = red[sub + 384];
        acc.x += a1.x + a2.x + a3.x;
        acc.y += a1.y + a2.y + a3.y;
        acc.z += a1.z + a2.z + a3.z;
        acc.w += a1.w + a2.w + a3.w;

        // |s|^2 across the 4 d-quads (dq = low 2 bits of lane id)
        float sq = acc.x*acc.x + acc.y*acc.y + acc.z*acc.z + acc.w*acc.w;
        sq += __shfl_xor(sq, 1);
        sq += __shfl_xor(sq, 2);
        const float scale = sq / ((1.0f + sq) * sqrtf(sq + SQ_EPS));

        if (phase == 3) {
            float4* op = reinterpret_cast<float4*>(out + ((size_t)b * NC + c) * DC + dq * 4);
            *op = make_float4(scale*acc.x, scale*acc.y, scale*acc.z, scale*acc.w);
        } else {
            const float ns = scale * (float)NI;
            float4* vp = reinterpret_cast<float4*>(
                veff + (((size_t)b * 2 + (dq >> 1)) * 32 + c) * 8 + (dq & 1) * 4);
            if (phase == 1) {
                *vp = make_float4(ns*acc.x, ns*acc.y, ns*acc.z, ns*acc.w);
            } else {
                float4 old = *vp;
                *vp = make_float4(old.x + ns*acc.x, old.y + ns*acc.y,
                                  old.z + ns*acc.z, old.w + ns*acc.w);
            }
        }
    }
}

extern "C" void kernel_launch(void* const* d_in, const int* in_sizes, int n_in,
                              void* d_out, int out_size, void* d_ws, size_t ws_size,
                              hipStream_t stream) {
    (void)in_sizes; (void)n_in; (void)out_size; (void)ws_size;
    const float* x = (const float*)d_in[0];
    const float* W = (const float*)d_in[1];

    float* partial = (float*)d_ws;      // 512 slabs x 32 KB = 16 MiB
    float* veff    = (float*)d_out;     // scratch; phase-3 squash overwrites

    const dim3 grid(128, 4);

    // ---- iteration 1: uniform coupling
    route_pass<0><<<grid, 256, 0, stream>>>(x, W, nullptr, partial);
    reduce_squash<<<64, 512, 0, stream>>>(partial, veff, nullptr, 1);

    // ---- iteration 2: logits = NI * <u, v1>
    route_pass<1><<<grid, 256, 0, stream>>>(x, W, veff, partial);
    reduce_squash<<<64, 512, 0, stream>>>(partial, veff, nullptr, 2);

    // ---- iteration 3: logits = NI * (<u, v1> + <u, v2>)
    route_pass<1><<<grid, 256, 0, stream>>>(x, W, veff, partial);
    reduce_squash<<<64, 512, 0, stream>>>(partial, nullptr, (float*)d_out, 3);
}